// Round 1
// 702.798 us; speedup vs baseline: 1.0743x; 1.0743x over previous
//
#include <hip/hip_runtime.h>
#include <cstdint>
#include <cstddef>

#define B_SZ 4096
#define H_SZ 2048
#define S_SZ 3

typedef __attribute__((ext_vector_type(8))) _Float16 f16x8;
typedef __attribute__((ext_vector_type(4))) float f32x4;

__device__ __forceinline__ void glds16(const void* g, void* l) {
    __builtin_amdgcn_global_load_lds(
        (const __attribute__((address_space(1))) void*)g,
        (__attribute__((address_space(3))) void*)l, 16, 0, 0);
}

__device__ __forceinline__ float wave_red_sum(float v) {
#pragma unroll
    for (int off = 32; off > 0; off >>= 1) v += __shfl_down(v, off);
    return v;
}

// ------------------------------------------------------------ f32 -> f16 ----
__global__ __launch_bounds__(256) void cvt_f16_kernel(
    const float* __restrict__ src, _Float16* __restrict__ dst, int n4)
{
    const int i = blockIdx.x * 256 + threadIdx.x;
    if (i >= n4) return;
    const float4 v = ((const float4*)src)[i];
    _Float16 h[4];
    h[0] = (_Float16)v.x; h[1] = (_Float16)v.y;
    h[2] = (_Float16)v.z; h[3] = (_Float16)v.w;
    *(uint2*)(dst + (size_t)i * 4) = *(const uint2*)h;
}

// ---------------------------------------------------------------- gate ------
__global__ __launch_bounds__(64) void gate_kernel(
    const float* __restrict__ prev_master, const float* __restrict__ gate_W,
    const float* __restrict__ gate_b, const float* __restrict__ gumbel,
    float* __restrict__ out_gate)
{
    const int b = blockIdx.x;
    const int lane = threadIdx.x;
    const float* row = prev_master + (size_t)b * H_SZ;
    double a0 = 0.0, a1 = 0.0, a2 = 0.0;
#pragma unroll
    for (int k = lane * 4; k < H_SZ; k += 64 * 4) {
        float4 v  = *(const float4*)(row + k);
        float4 w0 = *(const float4*)(gate_W + 0 * H_SZ + k);
        float4 w1 = *(const float4*)(gate_W + 1 * H_SZ + k);
        float4 w2 = *(const float4*)(gate_W + 2 * H_SZ + k);
        a0 += (double)v.x * w0.x + (double)v.y * w0.y + (double)v.z * w0.z + (double)v.w * w0.w;
        a1 += (double)v.x * w1.x + (double)v.y * w1.y + (double)v.z * w1.z + (double)v.w * w1.w;
        a2 += (double)v.x * w2.x + (double)v.y * w2.y + (double)v.z * w2.z + (double)v.w * w2.w;
    }
#pragma unroll
    for (int off = 32; off > 0; off >>= 1) {
        a0 += __shfl_down(a0, off);
        a1 += __shfl_down(a1, off);
        a2 += __shfl_down(a2, off);
    }
    if (lane == 0) {
        float z0 = (float)a0 + gate_b[0] + gumbel[b * 3 + 0];
        float z1 = (float)a1 + gate_b[1] + gumbel[b * 3 + 1];
        float z2 = (float)a2 + gate_b[2] + gumbel[b * 3 + 2];
        float zm = fmaxf(z0, fmaxf(z1, z2));
        float e0 = expf(z0 - zm), e1 = expf(z1 - zm), e2 = expf(z2 - zm);
        float se = e0 + e1 + e2;
        float y0 = e0 / se, y1 = e1 / se, y2 = e2 / se;
        int am = 0; float best = y0;
        if (y1 > best) { best = y1; am = 1; }
        if (y2 > best) { best = y2; am = 2; }
        float h0 = (am == 0) ? 1.0f : 0.0f;
        float h1 = (am == 1) ? 1.0f : 0.0f;
        float h2 = (am == 2) ? 1.0f : 0.0f;
        out_gate[b * 3 + 0] = (h0 + y0) - y0;
        out_gate[b * 3 + 1] = (h1 + y1) - y1;
        out_gate[b * 3 + 2] = (h2 + y2) - y2;
    }
}

// ------------------------------------------------- pipelined tile GEMM ------
// BM=128, BN=256, BK=32. 512 threads = 8 waves (2M x 4N), 64x64 per wave.
// 5-deep LDS ring (5 x 24KB = 120KB): stage tile t+4 while computing tile t.
// Counted s_waitcnt vmcnt(6) (2 tiles in flight), raw s_barrier — no
// __syncthreads() drain in the main loop. Frags of tile t+1 ds_read'd during
// tile t's MFMAs (ring guarantees t+1 landed at the previous sync).
// XOR chunk-swizzle (c ^ ((row>>1)&3)) -> conflict-free ds_read_b128 (proven
// 0-conflict in the previous kernel); staging pre-swizzles the global source.
// MODE 0: out[s,b,h] = tanh(x.Wih^T + sub.Whh^T + b_ih + b_hh), NT=128 (2 K phases)
// MODE 1: out[b,h]   = wtd.fusW^T + fusion_b + prev_master,     NT=64
template<int MODE, int NT>
__global__ __launch_bounds__(512, 2) void tile_gemm_kernel(
    const _Float16* __restrict__ A0, const _Float16* __restrict__ A1,
    const _Float16* __restrict__ W0, const _Float16* __restrict__ W1,
    const float* __restrict__ bias0, const float* __restrict__ bias1,
    const float* __restrict__ prev_master, float* __restrict__ out)
{
    __shared__ __align__(16) _Float16 lds[5 * 12288];  // per buf: A[128][32] | B[256][32]

    // bijective XCD swizzle (nwg % 8 == 0). M-tiles fastest inside a chunk:
    // each B-panel (256x4096 f16 = 2MB) stays L2-resident, reused 32x.
    const int flat = blockIdx.x;
    constexpr int QX = (MODE == 0) ? 96 : 32;          // nwg / 8
    const int L  = (flat & 7) * QX + (flat >> 3);
    const int ly = L & 31;                             // M-tile (32)
    const int lx = (L >> 5) & 7;                       // N-tile (8)
    const int s  = (MODE == 0) ? (L >> 8) : 0;
    const int am0 = ly * 128;
    const int n0  = lx * 256;

    const int tid  = threadIdx.x;
    const int lane = tid & 63;
    const int wave = tid >> 6;
    const int wm = wave >> 2;                          // 0..1
    const int wn = wave & 3;                           // 0..3
    const int lrow = lane & 15;
    const int fcol = ((lane >> 4) ^ ((lrow >> 1) & 3)) * 8;
    const int srow   = tid >> 2;                       // 0..127
    const int schunk = (tid & 3) ^ ((tid >> 3) & 3);   // pre-swizzled src chunk
    const int ldst   = wave << 9;                      // wave-uniform LDS elem base

    int roa[4], rob[4];
#pragma unroll
    for (int i = 0; i < 4; ++i) {
        roa[i] = (wm * 64 + i * 16 + lrow) * 32 + fcol;
        rob[i] = 4096 + (wn * 64 + i * 16 + lrow) * 32 + fcol;
    }

    f32x4 acc[4][4] = {};
    f16x8 fAa[4], fAb[4], fBa[4], fBb[4];

    auto stage = [&](int t, int bufe) {
        int kb; const _Float16 *As, *Ws;
        if constexpr (MODE == 0) {
            kb = (t & 63) * 32;
            if (t < 64) { As = A0;                             Ws = W0 + (size_t)s * (H_SZ * 2048); }
            else        { As = A1 + (size_t)s * (B_SZ * 2048); Ws = W1 + (size_t)s * (H_SZ * 2048); }
        } else {
            kb = t * 32; As = A0; Ws = W0;
        }
        const int ko = kb + schunk * 8;
        glds16(As + (size_t)(am0 + srow)       * 2048 + ko, &lds[bufe + ldst]);
        glds16(Ws + (size_t)(n0  + srow)       * 2048 + ko, &lds[bufe + 4096 + ldst]);
        glds16(Ws + (size_t)(n0  + 128 + srow) * 2048 + ko, &lds[bufe + 8192 + ldst]);
    };

    auto read_frags = [&](int bufe, f16x8 (&fa)[4], f16x8 (&fb)[4]) {
#pragma unroll
        for (int i = 0; i < 4; ++i) {
            fa[i] = *(const f16x8*)&lds[bufe + roa[i]];
            fb[i] = *(const f16x8*)&lds[bufe + rob[i]];
        }
    };

    auto mfma16 = [&](const f16x8 (&fa)[4], const f16x8 (&fb)[4]) {
        __builtin_amdgcn_s_setprio(1);
#pragma unroll
        for (int i = 0; i < 4; ++i)
#pragma unroll
            for (int j = 0; j < 4; ++j)
                acc[i][j] = __builtin_amdgcn_mfma_f32_16x16x32_f16(fa[i], fb[j], acc[i][j], 0, 0, 0);
        __builtin_amdgcn_s_setprio(0);
    };

    // after computing tile u: allow only tiles > u+1 in flight (3 loads each).
    auto sync_tile = [&](int u) {
        __builtin_amdgcn_sched_barrier(0);             // pin MFMAs/reads above
        if (u <= NT - 5)      asm volatile("s_waitcnt vmcnt(6)" ::: "memory");
        else if (u == NT - 4) asm volatile("s_waitcnt vmcnt(3)" ::: "memory");
        else if (u == NT - 3) asm volatile("s_waitcnt vmcnt(0)" ::: "memory");
        else return;                                   // tail: nothing pending
        __builtin_amdgcn_s_barrier();
        asm volatile("" ::: "memory");                 // no LDS-read hoist above barrier
    };

    // prologue: stage tiles 0..3 (12 loads); vmcnt(6) -> tiles 0,1 landed.
    stage(0, 0); stage(1, 12288); stage(2, 24576); stage(3, 36864);
    asm volatile("s_waitcnt vmcnt(6)" ::: "memory");
    __builtin_amdgcn_s_barrier();
    asm volatile("" ::: "memory");
    read_frags(0, fAa, fAb);

    int c = 0;                                         // t % 5
    for (int t = 0; t < NT; t += 2) {
        int b1 = c + 1; if (b1 >= 5) b1 -= 5;
        int b2 = c + 2; if (b2 >= 5) b2 -= 5;
        int b4 = c + 4; if (b4 >= 5) b4 -= 5;
        // ---- tile t: stage t+4, prefetch frags t+1, MFMA t ----
        if (t + 4 < NT) stage(t + 4, b4 * 12288);
        read_frags(b1 * 12288, fBa, fBb);
        mfma16(fAa, fAb);
        sync_tile(t);
        // ---- tile t+1: stage t+5, prefetch frags t+2, MFMA t+1 ----
        if (t + 5 < NT) stage(t + 5, c * 12288);
        if (t + 2 < NT) read_frags(b2 * 12288, fAa, fAb);
        mfma16(fBa, fBb);
        sync_tile(t + 1);
        c += 2; if (c >= 5) c -= 5;
    }

    // epilogue: C layout col = lane&15, row = (lane>>4)*4 + reg (verified)
#pragma unroll
    for (int j = 0; j < 4; ++j) {
        const int n = n0 + wn * 64 + j * 16 + lrow;
        float badd;
        if constexpr (MODE == 0) badd = bias0[s * H_SZ + n] + bias1[s * H_SZ + n];
        else                     badd = bias0[n];
#pragma unroll
        for (int i = 0; i < 4; ++i) {
            const int mb = am0 + wm * 64 + i * 16 + (lane >> 4) * 4;
#pragma unroll
            for (int r = 0; r < 4; ++r) {
                const int m = mb + r;
                if constexpr (MODE == 0)
                    out[((size_t)s * B_SZ + m) * H_SZ + n] = tanhf(acc[i][j][r] + badd);
                else
                    out[(size_t)m * H_SZ + n] =
                        acc[i][j][r] + badd + prev_master[(size_t)m * H_SZ + n];
            }
        }
    }
}

// ------------------------------------------------------------- weighted -----
__global__ __launch_bounds__(256) void weighted_kernel(
    const float* __restrict__ new_sub, const float* __restrict__ gate,
    _Float16* __restrict__ w16)
{
    const size_t p = (size_t)blockIdx.x * 256 + threadIdx.x;   // float4 index
    const size_t b = p / (H_SZ / 4);
    const int h4 = (int)(p % (H_SZ / 4)) * 4;
    const float g0 = gate[b * 3 + 0], g1 = gate[b * 3 + 1], g2 = gate[b * 3 + 2];
    const float4 v0 = *(const float4*)(new_sub + ((size_t)0 * B_SZ + b) * H_SZ + h4);
    const float4 v1 = *(const float4*)(new_sub + ((size_t)1 * B_SZ + b) * H_SZ + h4);
    const float4 v2 = *(const float4*)(new_sub + ((size_t)2 * B_SZ + b) * H_SZ + h4);
    _Float16 h[4];
    h[0] = (_Float16)(g0 * v0.x + g1 * v1.x + g2 * v2.x);
    h[1] = (_Float16)(g0 * v0.y + g1 * v1.y + g2 * v2.y);
    h[2] = (_Float16)(g0 * v0.z + g1 * v1.z + g2 * v2.z);
    h[3] = (_Float16)(g0 * v0.w + g1 * v1.w + g2 * v2.w);
    *(uint2*)(w16 + b * H_SZ + h4) = *(const uint2*)h;
}

// ------------------------------------------------------- layernorm+sigmoid --
__global__ __launch_bounds__(256) void ln_sigmoid_kernel(
    float* __restrict__ master, const float* __restrict__ ln_g,
    const float* __restrict__ ln_b)
{
    const int b = blockIdx.x;
    const int t = threadIdx.x;
    float* row = master + (size_t)b * H_SZ;
    float v[8];
    float4 p0 = *(const float4*)(row + t * 4);
    float4 p1 = *(const float4*)(row + 1024 + t * 4);
    v[0] = p0.x; v[1] = p0.y; v[2] = p0.z; v[3] = p0.w;
    v[4] = p1.x; v[5] = p1.y; v[6] = p1.z; v[7] = p1.w;
    float lsum = 0.f;
#pragma unroll
    for (int e = 0; e < 8; ++e) lsum += v[e];
    __shared__ float red[8];
    float wsum = wave_red_sum(lsum);
    const int lane = t & 63, wid = t >> 6;
    if (lane == 0) red[wid] = wsum;
    __syncthreads();
    const float mu = (red[0] + red[1] + red[2] + red[3]) * (1.0f / H_SZ);
    float lsq = 0.f;
#pragma unroll
    for (int e = 0; e < 8; ++e) { float d = v[e] - mu; lsq += d * d; }
    float wsq = wave_red_sum(lsq);
    if (lane == 0) red[4 + wid] = wsq;
    __syncthreads();
    const float var = (red[4] + red[5] + red[6] + red[7]) * (1.0f / H_SZ);
    const float rs = rsqrtf(var + 1e-5f);
#pragma unroll
    for (int half = 0; half < 2; ++half)
#pragma unroll
        for (int e = 0; e < 4; ++e) {
            const int col = half * 1024 + t * 4 + e;
            const float nm = (v[half * 4 + e] - mu) * rs * ln_g[col] + ln_b[col];
            row[col] = 1.0f / (1.0f + expf(-nm));
        }
}

// ----------------------------------------------------------------- launch ---
extern "C" void kernel_launch(void* const* d_in, const int* in_sizes, int n_in,
                              void* d_out, int out_size, void* d_ws, size_t ws_size,
                              hipStream_t stream)
{
    const float* x           = (const float*)d_in[0];
    const float* prev_master = (const float*)d_in[1];
    const float* prev_sub    = (const float*)d_in[2];
    const float* gumbel      = (const float*)d_in[3];
    const float* W_ih        = (const float*)d_in[4];
    const float* W_hh        = (const float*)d_in[5];
    const float* b_ih        = (const float*)d_in[6];
    const float* b_hh        = (const float*)d_in[7];
    const float* gate_W      = (const float*)d_in[8];
    const float* gate_b      = (const float*)d_in[9];
    const float* fusion_W    = (const float*)d_in[10];
    const float* fusion_b    = (const float*)d_in[11];
    const float* ln_g        = (const float*)d_in[12];
    const float* ln_b        = (const float*)d_in[13];

    float* out = (float*)d_out;
    float* out_master  = out;                                   // [B,H]
    float* out_gate    = out + (size_t)B_SZ * H_SZ;             // [B,S]
    float* out_new_sub = out_gate + (size_t)B_SZ * S_SZ;        // [S,B,H]

    // ws layout (fp16 planes), ~143 MB total
    _Float16* ws = (_Float16*)d_ws;
    _Float16* x16    = ws;                                      // 8.4M
    _Float16* sub16  = x16   + (size_t)B_SZ * H_SZ;             // 25.2M
    _Float16* Wih16  = sub16 + (size_t)S_SZ * B_SZ * H_SZ;      // 12.6M
    _Float16* Whh16  = Wih16 + (size_t)S_SZ * H_SZ * H_SZ;      // 12.6M
    _Float16* fusW16 = Whh16 + (size_t)S_SZ * H_SZ * H_SZ;      // 4.2M
    _Float16* wtd16  = fusW16 + (size_t)H_SZ * H_SZ;            // 8.4M

    const int n4_x   = B_SZ * H_SZ / 4;
    const int n4_sub = S_SZ * B_SZ * H_SZ / 4;
    const int n4_w   = S_SZ * H_SZ * H_SZ / 4;
    const int n4_fw  = H_SZ * H_SZ / 4;

    cvt_f16_kernel<<<n4_x / 256, 256, 0, stream>>>(x, x16, n4_x);
    cvt_f16_kernel<<<n4_sub / 256, 256, 0, stream>>>(prev_sub, sub16, n4_sub);
    cvt_f16_kernel<<<n4_w / 256, 256, 0, stream>>>(W_ih, Wih16, n4_w);
    cvt_f16_kernel<<<n4_w / 256, 256, 0, stream>>>(W_hh, Whh16, n4_w);
    cvt_f16_kernel<<<n4_fw / 256, 256, 0, stream>>>(fusion_W, fusW16, n4_fw);

    gate_kernel<<<B_SZ, 64, 0, stream>>>(prev_master, gate_W, gate_b, gumbel, out_gate);

    // sub-cell GEMMs: 768 blocks = 3 exact full waves of 256 CUs (no tail)
    tile_gemm_kernel<0, 128><<<768, 512, 0, stream>>>(
        x16, sub16, Wih16, Whh16, b_ih, b_hh, nullptr, out_new_sub);

    weighted_kernel<<<(B_SZ * (H_SZ / 4)) / 256, 256, 0, stream>>>(
        out_new_sub, out_gate, wtd16);

    // fusion GEMM: 256 blocks = 1 exact full wave
    tile_gemm_kernel<1, 64><<<256, 512, 0, stream>>>(
        wtd16, nullptr, fusW16, nullptr, fusion_b, nullptr, prev_master, out_master);

    ln_sigmoid_kernel<<<B_SZ, 256, 0, stream>>>(out_master, ln_g, ln_b);
}

// Round 3
// 669.978 us; speedup vs baseline: 1.1269x; 1.0490x over previous
//
#include <hip/hip_runtime.h>
#include <cstdint>
#include <cstddef>

#define B_SZ 4096
#define H_SZ 2048
#define S_SZ 3

typedef __attribute__((ext_vector_type(8))) _Float16 f16x8;
typedef __attribute__((ext_vector_type(4))) float f32x4;

__device__ __forceinline__ void glds16(const void* g, void* l) {
    __builtin_amdgcn_global_load_lds(
        (const __attribute__((address_space(1))) void*)g,
        (__attribute__((address_space(3))) void*)l, 16, 0, 0);
}

__device__ __forceinline__ float wave_red_sum(float v) {
#pragma unroll
    for (int off = 32; off > 0; off >>= 1) v += __shfl_down(v, off);
    return v;
}

// ------------------------------------------------------------ f32 -> f16 ----
// All five tensors in one launch. ws destinations are contiguous
// (x16|sub16|Wih16|Whh16|fusW16), so dst index == flat index; only src varies.
// Segment sizes are multiples of 256 float4s -> wave-uniform branches.
__global__ __launch_bounds__(256) void cvt_all_kernel(
    const float* __restrict__ s0, const float* __restrict__ s1,
    const float* __restrict__ s2, const float* __restrict__ s3,
    const float* __restrict__ s4, _Float16* __restrict__ dst)
{
    constexpr size_t c1 = (size_t)B_SZ * H_SZ / 4;             // x
    constexpr size_t c2 = c1 + (size_t)S_SZ * B_SZ * H_SZ / 4; // prev_sub
    constexpr size_t c3 = c2 + (size_t)S_SZ * H_SZ * H_SZ / 4; // W_ih
    constexpr size_t c4 = c3 + (size_t)S_SZ * H_SZ * H_SZ / 4; // W_hh
    const size_t i = (size_t)blockIdx.x * 256 + threadIdx.x;   // float4 index
    const float* src; size_t rel;
    if (i < c2)      { if (i < c1) { src = s0; rel = i; } else { src = s1; rel = i - c1; } }
    else if (i < c3) { src = s2; rel = i - c2; }
    else if (i < c4) { src = s3; rel = i - c3; }
    else             { src = s4; rel = i - c4; }
    const float4 v = ((const float4*)src)[rel];
    _Float16 h[4];
    h[0] = (_Float16)v.x; h[1] = (_Float16)v.y;
    h[2] = (_Float16)v.z; h[3] = (_Float16)v.w;
    *(uint2*)(dst + i * 4) = *(const uint2*)h;
}

// ---------------------------------------------------------------- gate ------
__global__ __launch_bounds__(64) void gate_kernel(
    const float* __restrict__ prev_master, const float* __restrict__ gate_W,
    const float* __restrict__ gate_b, const float* __restrict__ gumbel,
    float* __restrict__ out_gate)
{
    const int b = blockIdx.x;
    const int lane = threadIdx.x;
    const float* row = prev_master + (size_t)b * H_SZ;
    double a0 = 0.0, a1 = 0.0, a2 = 0.0;
#pragma unroll
    for (int k = lane * 4; k < H_SZ; k += 64 * 4) {
        float4 v  = *(const float4*)(row + k);
        float4 w0 = *(const float4*)(gate_W + 0 * H_SZ + k);
        float4 w1 = *(const float4*)(gate_W + 1 * H_SZ + k);
        float4 w2 = *(const float4*)(gate_W + 2 * H_SZ + k);
        a0 += (double)v.x * w0.x + (double)v.y * w0.y + (double)v.z * w0.z + (double)v.w * w0.w;
        a1 += (double)v.x * w1.x + (double)v.y * w1.y + (double)v.z * w1.z + (double)v.w * w1.w;
        a2 += (double)v.x * w2.x + (double)v.y * w2.y + (double)v.z * w2.z + (double)v.w * w2.w;
    }
#pragma unroll
    for (int off = 32; off > 0; off >>= 1) {
        a0 += __shfl_down(a0, off);
        a1 += __shfl_down(a1, off);
        a2 += __shfl_down(a2, off);
    }
    if (lane == 0) {
        float z0 = (float)a0 + gate_b[0] + gumbel[b * 3 + 0];
        float z1 = (float)a1 + gate_b[1] + gumbel[b * 3 + 1];
        float z2 = (float)a2 + gate_b[2] + gumbel[b * 3 + 2];
        float zm = fmaxf(z0, fmaxf(z1, z2));
        float e0 = expf(z0 - zm), e1 = expf(z1 - zm), e2 = expf(z2 - zm);
        float se = e0 + e1 + e2;
        float y0 = e0 / se, y1 = e1 / se, y2 = e2 / se;
        int am = 0; float best = y0;
        if (y1 > best) { best = y1; am = 1; }
        if (y2 > best) { best = y2; am = 2; }
        float h0 = (am == 0) ? 1.0f : 0.0f;
        float h1 = (am == 1) ? 1.0f : 0.0f;
        float h2 = (am == 2) ? 1.0f : 0.0f;
        out_gate[b * 3 + 0] = (h0 + y0) - y0;
        out_gate[b * 3 + 1] = (h1 + y1) - y1;
        out_gate[b * 3 + 2] = (h2 + y2) - y2;
    }
}

// ------------------------------------------------- pipelined tile GEMM ------
// BM=128, BN=256, BK=32. 256 threads = 4 waves (1M x 4N), 128x64 per wave.
// Per-wave frags: A reused 4x, B reused 8x -> 384 B/MFMA = 42.7 FLOP/B on LDS
// (vs 32 at 64x64/wave) — LDS read pipe no longer over the MFMA pipe.
// Ring-3 LDS (3 x 24KB = 72KB) -> 2 blocks/CU (8 waves/CU): cross-block
// overlap hides frag-read latency and barrier slack.
// Counted s_waitcnt vmcnt(6): tile t+2's 6 glds stay in flight across the
// barrier; never drained to 0 in the main loop.
// XOR chunk-swizzle (c ^ ((row>>1)&3)) -> conflict-free ds_read_b128 (0
// conflicts measured in rounds 0-1); staging pre-swizzles the global source.
// MODE 0: out[s,b,h] = tanh(x.Wih^T + sub.Whh^T + b_ih + b_hh), NT=128 (2 K phases)
// MODE 1: out[b,h]   = wtd.fusW^T + fusion_b + prev_master,     NT=64
template<int MODE, int NT>
__global__ __launch_bounds__(256, 2) void tile_gemm_kernel(
    const _Float16* __restrict__ A0, const _Float16* __restrict__ A1,
    const _Float16* __restrict__ W0, const _Float16* __restrict__ W1,
    const float* __restrict__ bias0, const float* __restrict__ bias1,
    const float* __restrict__ prev_master, float* __restrict__ out)
{
    __shared__ __align__(16) _Float16 lds[3 * 12288]; // per buf: A[128][32] | B[256][32]

    // bijective XCD swizzle (nwg % 8 == 0). M-tiles fastest inside a chunk:
    // each B-panel (256 rows x 2048 K f16 = 1MB/phase) stays L2-resident, 32x reuse.
    const int flat = blockIdx.x;
    constexpr int QX = (MODE == 0) ? 96 : 32;          // nwg / 8
    const int L  = (flat & 7) * QX + (flat >> 3);
    const int ly = L & 31;                             // M-tile (32)
    const int lx = (L >> 5) & 7;                       // N-tile (8)
    const int s  = (MODE == 0) ? (L >> 8) : 0;
    const int am0 = ly * 128;
    const int n0  = lx * 256;

    const int tid  = threadIdx.x;
    const int lane = tid & 63;
    const int wave = tid >> 6;                         // owns cols [wave*64, +64)
    const int lrow = lane & 15;
    const int fcol = ((lane >> 4) ^ ((lrow >> 1) & 3)) * 8;
    const int srow   = lane >> 2;                      // 0..15 within a 16-row slot
    const int schunk = (lane & 3) ^ ((lane >> 3) & 3); // pre-swizzled src chunk

    f32x4 acc[8][4] = {};

    // stage one 24KB tile: A = 8 slots x 1KB, B = 16 slots x 1KB; wave w takes
    // A slots {w, w+4}, B slots {w, w+4, w+8, w+12} -> 6 glds/thread.
    auto stage = [&](int t, int buf) {
        int kb; const _Float16 *As, *Ws;
        if constexpr (MODE == 0) {
            kb = (t & 63) * 32;
            if (t < 64) { As = A0;                             Ws = W0 + (size_t)s * (H_SZ * 2048); }
            else        { As = A1 + (size_t)s * (B_SZ * 2048); Ws = W1 + (size_t)s * (H_SZ * 2048); }
        } else {
            kb = t * 32; As = A0; Ws = W0;
        }
        const int ko = kb + schunk * 8;
        const int be = buf * 12288;
#pragma unroll
        for (int u = 0; u < 2; ++u) {
            const int slot = wave + u * 4;
            glds16(As + (size_t)(am0 + slot * 16 + srow) * 2048 + ko,
                   &lds[be + slot * 512]);
        }
#pragma unroll
        for (int u = 0; u < 4; ++u) {
            const int slot = wave + u * 4;
            glds16(Ws + (size_t)(n0 + slot * 16 + srow) * 2048 + ko,
                   &lds[be + 4096 + slot * 512]);
        }
    };

    // prologue: stage tiles 0,1 (12 loads); vmcnt(6) -> tile 0 landed.
    stage(0, 0); stage(1, 1);
    asm volatile("s_waitcnt vmcnt(6)" ::: "memory");
    __builtin_amdgcn_s_barrier();
    asm volatile("" ::: "memory");

    int cb = 0, cs = 2;                                // t%3, (t+2)%3
#pragma unroll 1
    for (int t = 0; t < NT; ++t) {
        if (t + 2 < NT) stage(t + 2, cs);
        const int be = cb * 12288;
        f16x8 af[8], bf[4];
#pragma unroll
        for (int i = 0; i < 8; ++i)
            af[i] = *(const f16x8*)&lds[be + (i * 16 + lrow) * 32 + fcol];
#pragma unroll
        for (int j = 0; j < 4; ++j)
            bf[j] = *(const f16x8*)&lds[be + 4096 + (wave * 64 + j * 16 + lrow) * 32 + fcol];
        __builtin_amdgcn_s_setprio(1);
#pragma unroll
        for (int i = 0; i < 8; ++i)
#pragma unroll
            for (int j = 0; j < 4; ++j)
                acc[i][j] = __builtin_amdgcn_mfma_f32_16x16x32_f16(af[i], bf[j], acc[i][j], 0, 0, 0);
        __builtin_amdgcn_s_setprio(0);
        __builtin_amdgcn_sched_barrier(0);             // pin reads/MFMAs above wait
        if (t < NT - 2)       asm volatile("s_waitcnt vmcnt(6)" ::: "memory");
        else if (t == NT - 2) asm volatile("s_waitcnt vmcnt(0)" ::: "memory");
        else break;                                    // last tile: no sync needed
        __builtin_amdgcn_s_barrier();
        asm volatile("" ::: "memory");                 // no LDS-read hoist above barrier
        cb = (cb == 2) ? 0 : cb + 1;
        cs = (cs == 2) ? 0 : cs + 1;
    }

    // epilogue: C layout col = lane&15, row = (lane>>4)*4 + reg (verified)
#pragma unroll
    for (int j = 0; j < 4; ++j) {
        const int n = n0 + wave * 64 + j * 16 + lrow;
        float badd;
        if constexpr (MODE == 0) badd = bias0[s * H_SZ + n] + bias1[s * H_SZ + n];
        else                     badd = bias0[n];
#pragma unroll
        for (int i = 0; i < 8; ++i) {
            const int mb = am0 + i * 16 + (lane >> 4) * 4;
#pragma unroll
            for (int r = 0; r < 4; ++r) {
                const int m = mb + r;
                if constexpr (MODE == 0)
                    out[((size_t)s * B_SZ + m) * H_SZ + n] = tanhf(acc[i][j][r] + badd);
                else
                    out[(size_t)m * H_SZ + n] =
                        acc[i][j][r] + badd + prev_master[(size_t)m * H_SZ + n];
            }
        }
    }
}

// ------------------------------------------------------------- weighted -----
__global__ __launch_bounds__(256) void weighted_kernel(
    const float* __restrict__ new_sub, const float* __restrict__ gate,
    _Float16* __restrict__ w16)
{
    const size_t p = (size_t)blockIdx.x * 256 + threadIdx.x;   // float4 index
    const size_t b = p / (H_SZ / 4);
    const int h4 = (int)(p % (H_SZ / 4)) * 4;
    const float g0 = gate[b * 3 + 0], g1 = gate[b * 3 + 1], g2 = gate[b * 3 + 2];
    const float4 v0 = *(const float4*)(new_sub + ((size_t)0 * B_SZ + b) * H_SZ + h4);
    const float4 v1 = *(const float4*)(new_sub + ((size_t)1 * B_SZ + b) * H_SZ + h4);
    const float4 v2 = *(const float4*)(new_sub + ((size_t)2 * B_SZ + b) * H_SZ + h4);
    _Float16 h[4];
    h[0] = (_Float16)(g0 * v0.x + g1 * v1.x + g2 * v2.x);
    h[1] = (_Float16)(g0 * v0.y + g1 * v1.y + g2 * v2.y);
    h[2] = (_Float16)(g0 * v0.z + g1 * v1.z + g2 * v2.z);
    h[3] = (_Float16)(g0 * v0.w + g1 * v1.w + g2 * v2.w);
    *(uint2*)(w16 + b * H_SZ + h4) = *(const uint2*)h;
}

// ------------------------------------------------------- layernorm+sigmoid --
__global__ __launch_bounds__(256) void ln_sigmoid_kernel(
    float* __restrict__ master, const float* __restrict__ ln_g,
    const float* __restrict__ ln_b)
{
    const int b = blockIdx.x;
    const int t = threadIdx.x;
    float* row = master + (size_t)b * H_SZ;
    float v[8];
    float4 p0 = *(const float4*)(row + t * 4);
    float4 p1 = *(const float4*)(row + 1024 + t * 4);
    v[0] = p0.x; v[1] = p0.y; v[2] = p0.z; v[3] = p0.w;
    v[4] = p1.x; v[5] = p1.y; v[6] = p1.z; v[7] = p1.w;
    float lsum = 0.f;
#pragma unroll
    for (int e = 0; e < 8; ++e) lsum += v[e];
    __shared__ float red[8];
    float wsum = wave_red_sum(lsum);
    const int lane = t & 63, wid = t >> 6;
    if (lane == 0) red[wid] = wsum;
    __syncthreads();
    const float mu = (red[0] + red[1] + red[2] + red[3]) * (1.0f / H_SZ);
    float lsq = 0.f;
#pragma unroll
    for (int e = 0; e < 8; ++e) { float d = v[e] - mu; lsq += d * d; }
    float wsq = wave_red_sum(lsq);
    if (lane == 0) red[4 + wid] = wsq;
    __syncthreads();
    const float var = (red[4] + red[5] + red[6] + red[7]) * (1.0f / H_SZ);
    const float rs = rsqrtf(var + 1e-5f);
#pragma unroll
    for (int half = 0; half < 2; ++half)
#pragma unroll
        for (int e = 0; e < 4; ++e) {
            const int col = half * 1024 + t * 4 + e;
            const float nm = (v[half * 4 + e] - mu) * rs * ln_g[col] + ln_b[col];
            row[col] = 1.0f / (1.0f + expf(-nm));
        }
}

// ----------------------------------------------------------------- launch ---
extern "C" void kernel_launch(void* const* d_in, const int* in_sizes, int n_in,
                              void* d_out, int out_size, void* d_ws, size_t ws_size,
                              hipStream_t stream)
{
    const float* x           = (const float*)d_in[0];
    const float* prev_master = (const float*)d_in[1];
    const float* prev_sub    = (const float*)d_in[2];
    const float* gumbel      = (const float*)d_in[3];
    const float* W_ih        = (const float*)d_in[4];
    const float* W_hh        = (const float*)d_in[5];
    const float* b_ih        = (const float*)d_in[6];
    const float* b_hh        = (const float*)d_in[7];
    const float* gate_W      = (const float*)d_in[8];
    const float* gate_b      = (const float*)d_in[9];
    const float* fusion_W    = (const float*)d_in[10];
    const float* fusion_b    = (const float*)d_in[11];
    const float* ln_g        = (const float*)d_in[12];
    const float* ln_b        = (const float*)d_in[13];

    float* out = (float*)d_out;
    float* out_master  = out;                                   // [B,H]
    float* out_gate    = out + (size_t)B_SZ * H_SZ;             // [B,S]
    float* out_new_sub = out_gate + (size_t)B_SZ * S_SZ;        // [S,B,H]

    // ws layout (fp16 planes, contiguous in cvt_all order)
    _Float16* ws = (_Float16*)d_ws;
    _Float16* x16    = ws;                                      // 8.4M
    _Float16* sub16  = x16   + (size_t)B_SZ * H_SZ;             // 25.2M
    _Float16* Wih16  = sub16 + (size_t)S_SZ * B_SZ * H_SZ;      // 12.6M
    _Float16* Whh16  = Wih16 + (size_t)S_SZ * H_SZ * H_SZ;      // 12.6M
    _Float16* fusW16 = Whh16 + (size_t)S_SZ * H_SZ * H_SZ;      // 4.2M
    _Float16* wtd16  = fusW16 + (size_t)H_SZ * H_SZ;            // 8.4M

    // single fused conversion: 15,728,640 float4s / 256 = 61440 blocks exact
    const int n4_total = (B_SZ * H_SZ + S_SZ * B_SZ * H_SZ + 2 * S_SZ * H_SZ * H_SZ
                          + H_SZ * H_SZ) / 4;
    cvt_all_kernel<<<n4_total / 256, 256, 0, stream>>>(
        x, prev_sub, W_ih, W_hh, fusion_W, ws);

    gate_kernel<<<B_SZ, 64, 0, stream>>>(prev_master, gate_W, gate_b, gumbel, out_gate);

    // sub-cell GEMMs: 768 blocks (2 resident/CU), 256 threads
    tile_gemm_kernel<0, 128><<<768, 256, 0, stream>>>(
        x16, sub16, Wih16, Whh16, b_ih, b_hh, nullptr, out_new_sub);

    weighted_kernel<<<(B_SZ * (H_SZ / 4)) / 256, 256, 0, stream>>>(
        out_new_sub, out_gate, wtd16);

    // fusion GEMM: 256 blocks
    tile_gemm_kernel<1, 64><<<256, 256, 0, stream>>>(
        wtd16, nullptr, fusW16, nullptr, fusion_b, nullptr, prev_master, out_master);

    ln_sigmoid_kernel<<<B_SZ, 256, 0, stream>>>(out_master, ln_g, ln_b);
}